// Round 15
// baseline (207.606 us; speedup 1.0000x reference)
//
#include <hip/hip_runtime.h>
#include <hip/hip_fp16.h>

// 2-layer GCN (PyG GCNConv), fp32 math — per-node CSR gather, fp16 payloads,
// 4-byte colpk edge entries. Round-15: (a) revert r14's ta/tb split (neutral:
// CSR build is LDS-atomic/latency bound, not traffic bound); (b) fuse gemm1
// into k_sortb — each bucket block, having dinv for its 512 nodes in LDS,
// computes g1h = fp16(dinv.*(x@W1)) for those rows (W1 tile in LDS). The
// ~5 us of GEMM VALU hides under sortb's latency stalls; one dispatch + gap
// removed. Pipeline: memset + part + sortb(+gemm1) + gfuse + gather32.
//
// g1h = fp16( dinv .* (x@W1) )
// acc[r] = g1h[r] + sum_{e:dst=r} w_e * g1h[src_e]   (fp32 regs; self w=1)
// x2 = relu(dinv[r]*acc[r] + b1);  g2h = fp16( dinv .* (x2@W2) )   [fused]
// out[r] = dinv[r]*(g2h[r] + sum_j w_j*g2h[src_j]) + b2

#define TPB 256
#define TPB_P 512
#define TPB_S 1024
#define BSH2 9
#define BN2 512
#define NBC 256          // coarse bucket slots (196 used)
#define PCHUNK 4096
#define CAP2 10752       // slots/bucket: 8192 + tail margin + <=3/node pads
#define XSTR 68          // x2 LDS row stride (floats)

typedef union { uint2 u; __half2 h[2]; } hpack;
typedef union { uint4 u; __half2 h[4]; } hpack8;

__device__ __forceinline__ int enc_w(float w) {  // bf16 RNE, sign dropped
  unsigned b = __float_as_uint(w);
  return (int)(((b + 0x7FFFu + ((b >> 16) & 1u)) >> 16) & 0x7FFFu);
}
__device__ __forceinline__ float dec_w(int e) {
  return __uint_as_float(((unsigned)e >> 17) << 16);
}

// phase A: per-chunk LDS counting sort by coarse bucket, then linear copy-out.
// tin entry = (src | dl9<<17, ew fp32). bpos[b] = running count (memset 0).
__global__ __launch_bounds__(TPB_P) void k_part(const int* __restrict__ si,
                                                const int* __restrict__ di,
                                                const float* __restrict__ ew,
                                                int* __restrict__ bpos,
                                                int2* __restrict__ tin, int e) {
  __shared__ int hcnt[NBC];
  __shared__ int lst0[NBC];
  __shared__ int lcur[NBC];
  __shared__ int hbase[NBC];
  __shared__ int2 se[PCHUNK];
  __shared__ unsigned char sbk[PCHUNK];
  int t = threadIdx.x;
  int lo = blockIdx.x * PCHUNK;
  int hi = lo + PCHUNK; if (hi > e) hi = e;
  int cn = hi - lo;
  if (t < NBC) hcnt[t] = 0;
  __syncthreads();
  for (int i = lo + t; i < hi; i += TPB_P) atomicAdd(&hcnt[di[i] >> BSH2], 1);
  __syncthreads();
  int c = (t < NBC) ? hcnt[t] : 0;
  for (int off = 1; off < NBC; off <<= 1) {
    int u = (t >= off && t < NBC) ? hcnt[t - off] : 0;
    __syncthreads();
    if (t < NBC) hcnt[t] += u;
    __syncthreads();
  }
  if (t < NBC) {
    int ex = hcnt[t] - c;
    lst0[t] = ex;
    lcur[t] = 0;
    hbase[t] = c ? (t * CAP2 + atomicAdd(&bpos[t], c)) : 0;
  }
  __syncthreads();
  for (int i = lo + t; i < hi; i += TPB_P) {
    int d = di[i];
    int bk = d >> BSH2;
    int loc = atomicAdd(&lcur[bk], 1);
    int p = lst0[bk] + loc;
    se[p] = make_int2(si[i] | ((d & (BN2 - 1)) << 17), __float_as_int(ew[i]));
    sbk[p] = (unsigned char)bk;
  }
  __syncthreads();
  for (int p = t; p < cn; p += TPB_P) {  // sequential stores within runs
    int bk = sbk[p];
    tin[hbase[bk] + (p - lst0[bk])] = se[p];
  }
}

// phase B: per-coarse-bucket (512 nodes) counting sort -> per-node 4B edge
// lists (x4-padded, 16B-aligned) + rowseg + dinv, PLUS fused layer-1 GEMM:
// g1h[r] = fp16(dinv[r] * (x[r] @ W1)) for the bucket's 512 rows.
__global__ __launch_bounds__(TPB_S) void k_sortb(const int2* __restrict__ tin,
                                                 const int* __restrict__ bpos,
                                                 int* __restrict__ colpk,
                                                 int2* __restrict__ rowseg,
                                                 float* __restrict__ dinv,
                                                 const float* __restrict__ x,
                                                 const float* __restrict__ W1,
                                                 __half* __restrict__ g1h, int n) {
  __shared__ int cnt[BN2];
  __shared__ float degw[BN2];
  __shared__ int cur[BN2];
  __shared__ int ls[BN2];
  __shared__ float W1l[64 * 64];
  int b = blockIdx.x, t = threadIdx.x;
  if (t < BN2) { cnt[t] = 0; degw[t] = 1.0f; }  // self-loop weight
  ((float4*)W1l)[t] = ((const float4*)W1)[t];   // 1024 thr x 16B = 16 KB
  __syncthreads();
  int jb = b * CAP2, je = jb + bpos[b];
  for (int j = jb + t; j < je; j += TPB_S) {
    int2 p = tin[j];
    int dl = p.x >> 17;
    atomicAdd(&cnt[dl], 1);
    atomicAdd(&degw[dl], __int_as_float(p.y));  // fp32 degree
  }
  __syncthreads();
  int c = (t < BN2) ? cnt[t] : 0;
  int c4 = (c + 3) & ~3;  // pad to multiple of 4 entries (16B)
  if (t < BN2) ls[t] = c4;
  __syncthreads();
  for (int off = 1; off < BN2; off <<= 1) {
    int u = (t >= off && t < BN2) ? ls[t - off] : 0;
    __syncthreads();
    if (t < BN2) ls[t] += u;
    __syncthreads();
  }
  int base = b << BSH2;
  if (t < BN2) {
    int start = jb + ls[t] - c4;  // 4-aligned offset -> 16B-aligned
    cur[t] = start;
    int node = base + t;
    if (node < n) {
      rowseg[node] = make_int2(start, start + c4);
      dinv[node] = rsqrtf(degw[t]);
    }
    for (int i = c; i < c4; ++i) colpk[start + i] = 0;  // zero-weight pads
  }
  __syncthreads();
  for (int j = jb + t; j < je; j += TPB_S) {
    int2 p = tin[j];
    int dl = p.x >> 17;
    int pos = atomicAdd(&cur[dl], 1);
    colpk[pos] = (p.x & 0x1FFFF) | (enc_w(__int_as_float(p.y)) << 17);
  }
  // ---- fused layer-1 GEMM for this bucket's rows (degw/W1l stable) ----
  int c0 = (t & 15) << 2;
  for (int rr = (t >> 4); rr < BN2; rr += 64) {  // 64 rows per pass
    int r = base + rr;
    if (r >= n) continue;
    const float4* xr = (const float4*)(x + (size_t)r * 64);
    float ax = 0.f, ay = 0.f, az = 0.f, aw = 0.f;
#pragma unroll
    for (int kk = 0; kk < 16; ++kk) {
      float4 xv = xr[kk];
      const float* w = &W1l[(kk * 4) * 64 + c0];
      float4 w0 = *(const float4*)(w);
      float4 w1 = *(const float4*)(w + 64);
      float4 w2 = *(const float4*)(w + 128);
      float4 w3 = *(const float4*)(w + 192);
      ax += xv.x * w0.x + xv.y * w1.x + xv.z * w2.x + xv.w * w3.x;
      ay += xv.x * w0.y + xv.y * w1.y + xv.z * w2.y + xv.w * w3.y;
      az += xv.x * w0.z + xv.y * w1.z + xv.z * w2.z + xv.w * w3.z;
      aw += xv.x * w0.w + xv.y * w1.w + xv.z * w2.w + xv.w * w3.w;
    }
    float dv = rsqrtf(degw[rr]);
    hpack pk;
    pk.h[0] = __floats2half2_rn(dv * ax, dv * ay);
    pk.h[1] = __floats2half2_rn(dv * az, dv * aw);
    *(uint2*)(g1h + (size_t)r * 64 + c0) = pk.u;
  }
}

// FUSED gather64 + gemm2. 32 nodes/block, 8 thr/node x 8 ch gather ->
// x2 = relu(dinv*acc + b1) -> LDS tile -> g2h = fp16(dinv .* (x2 @ W2)).
__global__ __launch_bounds__(TPB) void k_gfuse(const __half* __restrict__ g1h,
                                               const int* __restrict__ colpk,
                                               const int2* __restrict__ rowseg,
                                               const float* __restrict__ dinv,
                                               const float* __restrict__ W2,
                                               const float* __restrict__ b1,
                                               __half* __restrict__ g2h, int n) {
  __shared__ float W2l[64 * 32];
  __shared__ float b1l[64];
  __shared__ float x2l[32 * XSTR];
  int t = threadIdx.x;
  {
    const float4* W4 = (const float4*)W2;
    float4* Wl4 = (float4*)W2l;
#pragma unroll
    for (int i = 0; i < 2; ++i) Wl4[t + TPB * i] = W4[t + TPB * i];
    if (t < 64) b1l[t] = b1[t];
  }
  int node = t >> 3;
  int r = blockIdx.x * 32 + node;
  int c0 = (t & 7) << 3;
  bool valid = (r < n);
  float a[8];
  float dv = 0.f;
  if (valid) {
    dv = dinv[r];
    hpack8 s; s.u = *(const uint4*)(g1h + (size_t)r * 64 + c0);  // self-loop
#pragma unroll
    for (int k = 0; k < 4; ++k) {
      float2 f = __half22float2(s.h[k]);
      a[2 * k] = f.x; a[2 * k + 1] = f.y;
    }
    int2 seg = rowseg[r];
    int j = seg.x;
    for (; j + 7 < seg.y; j += 8) {
      int4 qa = *(const int4*)(colpk + j);
      int4 qb = *(const int4*)(colpk + j + 4);
      hpack8 u0; u0.u = *(const uint4*)(g1h + (size_t)(qa.x & 0x1FFFF) * 64 + c0);
      hpack8 u1; u1.u = *(const uint4*)(g1h + (size_t)(qa.y & 0x1FFFF) * 64 + c0);
      hpack8 u2; u2.u = *(const uint4*)(g1h + (size_t)(qa.z & 0x1FFFF) * 64 + c0);
      hpack8 u3; u3.u = *(const uint4*)(g1h + (size_t)(qa.w & 0x1FFFF) * 64 + c0);
      hpack8 u4; u4.u = *(const uint4*)(g1h + (size_t)(qb.x & 0x1FFFF) * 64 + c0);
      hpack8 u5; u5.u = *(const uint4*)(g1h + (size_t)(qb.y & 0x1FFFF) * 64 + c0);
      hpack8 u6; u6.u = *(const uint4*)(g1h + (size_t)(qb.z & 0x1FFFF) * 64 + c0);
      hpack8 u7; u7.u = *(const uint4*)(g1h + (size_t)(qb.w & 0x1FFFF) * 64 + c0);
      float w0 = dec_w(qa.x), w1 = dec_w(qa.y), w2 = dec_w(qa.z), w3 = dec_w(qa.w);
      float w4 = dec_w(qb.x), w5 = dec_w(qb.y), w6 = dec_w(qb.z), w7 = dec_w(qb.w);
#pragma unroll
      for (int k = 0; k < 4; ++k) {
        float2 f;
        f = __half22float2(u0.h[k]); a[2*k] += w0 * f.x; a[2*k+1] += w0 * f.y;
        f = __half22float2(u1.h[k]); a[2*k] += w1 * f.x; a[2*k+1] += w1 * f.y;
        f = __half22float2(u2.h[k]); a[2*k] += w2 * f.x; a[2*k+1] += w2 * f.y;
        f = __half22float2(u3.h[k]); a[2*k] += w3 * f.x; a[2*k+1] += w3 * f.y;
        f = __half22float2(u4.h[k]); a[2*k] += w4 * f.x; a[2*k+1] += w4 * f.y;
        f = __half22float2(u5.h[k]); a[2*k] += w5 * f.x; a[2*k+1] += w5 * f.y;
        f = __half22float2(u6.h[k]); a[2*k] += w6 * f.x; a[2*k+1] += w6 * f.y;
        f = __half22float2(u7.h[k]); a[2*k] += w7 * f.x; a[2*k+1] += w7 * f.y;
      }
    }
    if (j < seg.y) {  // exactly 4 remain (x4-padded)
      int4 qa = *(const int4*)(colpk + j);
      hpack8 u0; u0.u = *(const uint4*)(g1h + (size_t)(qa.x & 0x1FFFF) * 64 + c0);
      hpack8 u1; u1.u = *(const uint4*)(g1h + (size_t)(qa.y & 0x1FFFF) * 64 + c0);
      hpack8 u2; u2.u = *(const uint4*)(g1h + (size_t)(qa.z & 0x1FFFF) * 64 + c0);
      hpack8 u3; u3.u = *(const uint4*)(g1h + (size_t)(qa.w & 0x1FFFF) * 64 + c0);
      float w0 = dec_w(qa.x), w1 = dec_w(qa.y), w2 = dec_w(qa.z), w3 = dec_w(qa.w);
#pragma unroll
      for (int k = 0; k < 4; ++k) {
        float2 f;
        f = __half22float2(u0.h[k]); a[2*k] += w0 * f.x; a[2*k+1] += w0 * f.y;
        f = __half22float2(u1.h[k]); a[2*k] += w1 * f.x; a[2*k+1] += w1 * f.y;
        f = __half22float2(u2.h[k]); a[2*k] += w2 * f.x; a[2*k+1] += w2 * f.y;
        f = __half22float2(u3.h[k]); a[2*k] += w3 * f.x; a[2*k+1] += w3 * f.y;
      }
    }
    float* xp = x2l + node * XSTR + c0;
#pragma unroll
    for (int k = 0; k < 8; k += 4) {
      float4 v = {fmaxf(dv * a[k + 0] + b1l[c0 + k + 0], 0.f),
                  fmaxf(dv * a[k + 1] + b1l[c0 + k + 1], 0.f),
                  fmaxf(dv * a[k + 2] + b1l[c0 + k + 2], 0.f),
                  fmaxf(dv * a[k + 3] + b1l[c0 + k + 3], 0.f)};
      *(float4*)(xp + k) = v;
    }
  }
  __syncthreads();
  if (!valid) return;
  int oc = (t & 7) << 2;
  const float* xr = x2l + node * XSTR;
  float ax = 0.f, ay = 0.f, az = 0.f, aw = 0.f;
#pragma unroll
  for (int kk = 0; kk < 16; ++kk) {
    float4 xv = *(const float4*)(xr + 4 * kk);
    const float* w = &W2l[(kk * 4) * 32 + oc];
    float4 w0 = *(const float4*)(w);
    float4 w1 = *(const float4*)(w + 32);
    float4 w2 = *(const float4*)(w + 64);
    float4 w3 = *(const float4*)(w + 96);
    ax += xv.x * w0.x + xv.y * w1.x + xv.z * w2.x + xv.w * w3.x;
    ay += xv.x * w0.y + xv.y * w1.y + xv.z * w2.y + xv.w * w3.y;
    az += xv.x * w0.z + xv.y * w1.z + xv.z * w2.z + xv.w * w3.z;
    aw += xv.x * w0.w + xv.y * w1.w + xv.z * w2.w + xv.w * w3.w;
  }
  hpack pk;
  pk.h[0] = __floats2half2_rn(dv * ax, dv * ay);
  pk.h[1] = __floats2half2_rn(dv * az, dv * aw);
  *(uint2*)(g2h + (size_t)r * 32 + oc) = pk.u;
}

// out[r] = dinv[r]*(g2h[r] + sum_j w_j*g2h[src_j]) + b2. 4 thr/node x 8 ch.
__global__ __launch_bounds__(TPB) void k_gather32(const __half* __restrict__ g2h,
                                                  const int* __restrict__ colpk,
                                                  const int2* __restrict__ rowseg,
                                                  const float* __restrict__ dinv,
                                                  const float* __restrict__ b2,
                                                  float* __restrict__ out, int n) {
  int t = threadIdx.x;
  int r = blockIdx.x * 64 + (t >> 2);
  if (r >= n) return;
  int c0 = (t & 3) << 3;
  float a[8];
  {
    hpack8 s; s.u = *(const uint4*)(g2h + (size_t)r * 32 + c0);  // self-loop
#pragma unroll
    for (int k = 0; k < 4; ++k) {
      float2 f = __half22float2(s.h[k]);
      a[2 * k] = f.x; a[2 * k + 1] = f.y;
    }
  }
  int2 seg = rowseg[r];
  int j = seg.x;
  for (; j + 7 < seg.y; j += 8) {
    int4 qa = *(const int4*)(colpk + j);
    int4 qb = *(const int4*)(colpk + j + 4);
    hpack8 u0; u0.u = *(const uint4*)(g2h + (size_t)(qa.x & 0x1FFFF) * 32 + c0);
    hpack8 u1; u1.u = *(const uint4*)(g2h + (size_t)(qa.y & 0x1FFFF) * 32 + c0);
    hpack8 u2; u2.u = *(const uint4*)(g2h + (size_t)(qa.z & 0x1FFFF) * 32 + c0);
    hpack8 u3; u3.u = *(const uint4*)(g2h + (size_t)(qa.w & 0x1FFFF) * 32 + c0);
    hpack8 u4; u4.u = *(const uint4*)(g2h + (size_t)(qb.x & 0x1FFFF) * 32 + c0);
    hpack8 u5; u5.u = *(const uint4*)(g2h + (size_t)(qb.y & 0x1FFFF) * 32 + c0);
    hpack8 u6; u6.u = *(const uint4*)(g2h + (size_t)(qb.z & 0x1FFFF) * 32 + c0);
    hpack8 u7; u7.u = *(const uint4*)(g2h + (size_t)(qb.w & 0x1FFFF) * 32 + c0);
    float w0 = dec_w(qa.x), w1 = dec_w(qa.y), w2 = dec_w(qa.z), w3 = dec_w(qa.w);
    float w4 = dec_w(qb.x), w5 = dec_w(qb.y), w6 = dec_w(qb.z), w7 = dec_w(qb.w);
#pragma unroll
    for (int k = 0; k < 4; ++k) {
      float2 f;
      f = __half22float2(u0.h[k]); a[2*k] += w0 * f.x; a[2*k+1] += w0 * f.y;
      f = __half22float2(u1.h[k]); a[2*k] += w1 * f.x; a[2*k+1] += w1 * f.y;
      f = __half22float2(u2.h[k]); a[2*k] += w2 * f.x; a[2*k+1] += w2 * f.y;
      f = __half22float2(u3.h[k]); a[2*k] += w3 * f.x; a[2*k+1] += w3 * f.y;
      f = __half22float2(u4.h[k]); a[2*k] += w4 * f.x; a[2*k+1] += w4 * f.y;
      f = __half22float2(u5.h[k]); a[2*k] += w5 * f.x; a[2*k+1] += w5 * f.y;
      f = __half22float2(u6.h[k]); a[2*k] += w6 * f.x; a[2*k+1] += w6 * f.y;
      f = __half22float2(u7.h[k]); a[2*k] += w7 * f.x; a[2*k+1] += w7 * f.y;
    }
  }
  if (j < seg.y) {  // exactly 4 remain
    int4 qa = *(const int4*)(colpk + j);
    hpack8 u0; u0.u = *(const uint4*)(g2h + (size_t)(qa.x & 0x1FFFF) * 32 + c0);
    hpack8 u1; u1.u = *(const uint4*)(g2h + (size_t)(qa.y & 0x1FFFF) * 32 + c0);
    hpack8 u2; u2.u = *(const uint4*)(g2h + (size_t)(qa.z & 0x1FFFF) * 32 + c0);
    hpack8 u3; u3.u = *(const uint4*)(g2h + (size_t)(qa.w & 0x1FFFF) * 32 + c0);
    float w0 = dec_w(qa.x), w1 = dec_w(qa.y), w2 = dec_w(qa.z), w3 = dec_w(qa.w);
#pragma unroll
    for (int k = 0; k < 4; ++k) {
      float2 f;
      f = __half22float2(u0.h[k]); a[2*k] += w0 * f.x; a[2*k+1] += w0 * f.y;
      f = __half22float2(u1.h[k]); a[2*k] += w1 * f.x; a[2*k+1] += w1 * f.y;
      f = __half22float2(u2.h[k]); a[2*k] += w2 * f.x; a[2*k+1] += w2 * f.y;
      f = __half22float2(u3.h[k]); a[2*k] += w3 * f.x; a[2*k+1] += w3 * f.y;
    }
  }
  float dv = dinv[r];
  const float4* b24 = (const float4*)(b2 + c0);
  float4 bb0 = b24[0], bb1 = b24[1];
  float* op = out + (size_t)r * 32 + c0;
  *(float4*)(op)     = make_float4(dv * a[0] + bb0.x, dv * a[1] + bb0.y,
                                   dv * a[2] + bb0.z, dv * a[3] + bb0.w);
  *(float4*)(op + 4) = make_float4(dv * a[4] + bb1.x, dv * a[5] + bb1.y,
                                   dv * a[6] + bb1.z, dv * a[7] + bb1.w);
}

extern "C" void kernel_launch(void* const* d_in, const int* in_sizes, int n_in,
                              void* d_out, int out_size, void* d_ws, size_t ws_size,
                              hipStream_t stream) {
  const float* x  = (const float*)d_in[0];
  const int* ei   = (const int*)d_in[1];
  const float* ew = (const float*)d_in[2];
  const float* W1 = (const float*)d_in[3];
  const float* b1 = (const float*)d_in[4];
  const float* W2 = (const float*)d_in[5];
  const float* b2 = (const float*)d_in[6];
  float* out = (float*)d_out;

  const int n = in_sizes[0] / 64;  // 100000
  const int e = in_sizes[1] / 2;   // 1600000
  const int* si = ei;
  const int* di = ei + e;
  const int NBc = (n + BN2 - 1) >> BSH2;  // 196 coarse buckets

  // workspace layout (float-sized units), ~54 MB.
  float* ws = (float*)d_ws;
  const size_t NP = 100352;
  const size_t SLOTS = (size_t)NBC * CAP2;            // 2.75M
  float*  dinv   = ws;                                // [NP]
  __half* g1h    = (__half*)(ws + NP);                // [n*64 halves]
  int2*   rowseg = (int2*)(ws + NP + (size_t)n * 32); // [NP]
  int*    bpos   = (int*)(rowseg + NP);               // [NBC] counts (memset 0)
  int*    colpk  = bpos + 1024;                       // [SLOTS] 4B entries
  int2*   tin    = (int2*)(colpk + SLOTS);            // [SLOTS] int2
  __half* g2h    = (__half*)(tin + SLOTS);            // [n*32 halves]

  int gb_part = (e + PCHUNK - 1) / PCHUNK;  // 391
  int gb_gf = (n + 31) / 32;
  int gb_g32 = (n + 63) / 64;

  hipMemsetAsync(bpos, 0, NBC * sizeof(int), stream);
  k_part<<<gb_part, TPB_P, 0, stream>>>(si, di, ew, bpos, tin, e);
  k_sortb<<<NBc, TPB_S, 0, stream>>>(tin, bpos, colpk, rowseg, dinv,
                                     x, W1, g1h, n);
  k_gfuse<<<gb_gf, TPB, 0, stream>>>(g1h, colpk, rowseg, dinv, W2, b1, g2h, n);
  k_gather32<<<gb_g32, TPB, 0, stream>>>(g2h, colpk, rowseg, dinv, b2, out, n);
}

// Round 16
// 201.903 us; speedup vs baseline: 1.0282x; 1.0282x over previous
//
#include <hip/hip_runtime.h>
#include <hip/hip_fp16.h>

// 2-layer GCN (PyG GCNConv), fp32 math — per-node CSR gather, fp16 payloads,
// 4-byte colpk edge entries. Round-16: (a) un-fuse gemm1 (r15 fusion hurt:
// it serialized inside an under-occupied kernel); (b) coarse buckets 512 ->
// 256 nodes, so k_sortb runs 391 blocks instead of 196 — r15 counters showed
// sortb at 25.6% occupancy purely from block count (0.77 blocks/CU).
//
// g1h = fp16( dinv .* (x@W1) )
// acc[r] = g1h[r] + sum_{e:dst=r} w_e * g1h[src_e]   (fp32 regs; self w=1)
// x2 = relu(dinv[r]*acc[r] + b1);  g2h = fp16( dinv .* (x2@W2) )   [fused]
// out[r] = dinv[r]*(g2h[r] + sum_j w_j*g2h[src_j]) + b2

#define TPB 256
#define TPB_P 512
#define TPB_S 1024
#define BSH2 8
#define BN2 256          // nodes per coarse bucket
#define NBC 512          // coarse bucket slots (391 used)
#define PCHUNK 4096
#define CAP2 5632        // slots/bucket: 4096 avg + 11sigma + <=3/node pads
#define XSTR 68          // x2 LDS row stride (floats)

typedef union { uint2 u; __half2 h[2]; } hpack;
typedef union { uint4 u; __half2 h[4]; } hpack8;

__device__ __forceinline__ int enc_w(float w) {  // bf16 RNE, sign dropped
  unsigned b = __float_as_uint(w);
  return (int)(((b + 0x7FFFu + ((b >> 16) & 1u)) >> 16) & 0x7FFFu);
}
__device__ __forceinline__ float dec_w(int e) {
  return __uint_as_float(((unsigned)e >> 17) << 16);
}

// phase A: per-chunk LDS counting sort by coarse bucket, then linear copy-out.
// tin entry = (src | dl8<<17, ew fp32). bpos[b] = running count (memset 0).
__global__ __launch_bounds__(TPB_P) void k_part(const int* __restrict__ si,
                                                const int* __restrict__ di,
                                                const float* __restrict__ ew,
                                                int* __restrict__ bpos,
                                                int2* __restrict__ tin, int e) {
  __shared__ int hcnt[NBC];
  __shared__ int lst0[NBC];
  __shared__ int lcur[NBC];
  __shared__ int hbase[NBC];
  __shared__ int2 se[PCHUNK];
  __shared__ unsigned short sbk[PCHUNK];
  int t = threadIdx.x;
  int lo = blockIdx.x * PCHUNK;
  int hi = lo + PCHUNK; if (hi > e) hi = e;
  int cn = hi - lo;
  hcnt[t] = 0;  // TPB_P == NBC
  __syncthreads();
  for (int i = lo + t; i < hi; i += TPB_P) atomicAdd(&hcnt[di[i] >> BSH2], 1);
  __syncthreads();
  int c = hcnt[t];
  for (int off = 1; off < NBC; off <<= 1) {
    int u = (t >= off) ? hcnt[t - off] : 0;
    __syncthreads();
    hcnt[t] += u;
    __syncthreads();
  }
  {
    int ex = hcnt[t] - c;
    lst0[t] = ex;
    lcur[t] = 0;
    hbase[t] = c ? (t * CAP2 + atomicAdd(&bpos[t], c)) : 0;
  }
  __syncthreads();
  for (int i = lo + t; i < hi; i += TPB_P) {
    int d = di[i];
    int bk = d >> BSH2;
    int loc = atomicAdd(&lcur[bk], 1);
    int p = lst0[bk] + loc;
    se[p] = make_int2(si[i] | ((d & (BN2 - 1)) << 17), __float_as_int(ew[i]));
    sbk[p] = (unsigned short)bk;
  }
  __syncthreads();
  for (int p = t; p < cn; p += TPB_P) {  // sequential stores within runs
    int bk = sbk[p];
    tin[hbase[bk] + (p - lst0[bk])] = se[p];
  }
}

// phase B: per-coarse-bucket (256 nodes) counting sort -> per-node 4B edge
// lists (x4-padded, 16B-aligned starts) + rowseg + dinv. 391 blocks.
__global__ __launch_bounds__(TPB_S) void k_sortb(const int2* __restrict__ tin,
                                                 const int* __restrict__ bpos,
                                                 int* __restrict__ colpk,
                                                 int2* __restrict__ rowseg,
                                                 float* __restrict__ dinv, int n) {
  __shared__ int cnt[BN2];
  __shared__ float degw[BN2];
  __shared__ int cur[BN2];
  __shared__ int ls[BN2];
  int b = blockIdx.x, t = threadIdx.x;
  if (t < BN2) { cnt[t] = 0; degw[t] = 1.0f; }  // self-loop weight
  __syncthreads();
  int jb = b * CAP2, je = jb + bpos[b];
  for (int j = jb + t; j < je; j += TPB_S) {
    int2 p = tin[j];
    int dl = p.x >> 17;
    atomicAdd(&cnt[dl], 1);
    atomicAdd(&degw[dl], __int_as_float(p.y));  // fp32 degree
  }
  __syncthreads();
  int c = (t < BN2) ? cnt[t] : 0;
  int c4 = (c + 3) & ~3;  // pad to multiple of 4 entries (16B)
  if (t < BN2) ls[t] = c4;
  __syncthreads();
  for (int off = 1; off < BN2; off <<= 1) {
    int u = (t >= off && t < BN2) ? ls[t - off] : 0;
    __syncthreads();
    if (t < BN2) ls[t] += u;
    __syncthreads();
  }
  int base = b << BSH2;
  if (t < BN2) {
    int start = jb + ls[t] - c4;  // 4-aligned offset -> 16B-aligned
    cur[t] = start;
    int node = base + t;
    if (node < n) {
      rowseg[node] = make_int2(start, start + c4);
      dinv[node] = rsqrtf(degw[t]);
    }
    for (int i = c; i < c4; ++i) colpk[start + i] = 0;  // zero-weight pads
  }
  __syncthreads();
  for (int j = jb + t; j < je; j += TPB_S) {
    int2 p = tin[j];
    int dl = p.x >> 17;
    int pos = atomicAdd(&cur[dl], 1);
    colpk[pos] = (p.x & 0x1FFFF) | (enc_w(__int_as_float(p.y)) << 17);
  }
}

// g1h = fp16(dinv .* (x @ W1)). 16 rows/block, 16 thr/row x 4 ch.
__global__ __launch_bounds__(TPB) void k_gemm1(const float* __restrict__ x,
                                               const float* __restrict__ W1,
                                               const float* __restrict__ dinv,
                                               __half* __restrict__ g1h, int n) {
  __shared__ float Wl[64 * 64];
  int t = threadIdx.x;
  {
    const float4* W4 = (const float4*)W1;
    float4* Wl4 = (float4*)Wl;
#pragma unroll
    for (int i = 0; i < 4; ++i) Wl4[t + TPB * i] = W4[t + TPB * i];
  }
  __syncthreads();
  int r = blockIdx.x * 16 + (t >> 4);
  if (r >= n) return;
  int c0 = (t & 15) << 2;
  const float4* xr = (const float4*)(x + (size_t)r * 64);
  float ax = 0.f, ay = 0.f, az = 0.f, aw = 0.f;
#pragma unroll
  for (int kk = 0; kk < 16; ++kk) {
    float4 xv = xr[kk];
    const float* w = &Wl[(kk * 4) * 64 + c0];
    float4 w0 = *(const float4*)(w);
    float4 w1 = *(const float4*)(w + 64);
    float4 w2 = *(const float4*)(w + 128);
    float4 w3 = *(const float4*)(w + 192);
    ax += xv.x * w0.x + xv.y * w1.x + xv.z * w2.x + xv.w * w3.x;
    ay += xv.x * w0.y + xv.y * w1.y + xv.z * w2.y + xv.w * w3.y;
    az += xv.x * w0.z + xv.y * w1.z + xv.z * w2.z + xv.w * w3.z;
    aw += xv.x * w0.w + xv.y * w1.w + xv.z * w2.w + xv.w * w3.w;
  }
  float dv = dinv[r];
  hpack pk;
  pk.h[0] = __floats2half2_rn(dv * ax, dv * ay);
  pk.h[1] = __floats2half2_rn(dv * az, dv * aw);
  *(uint2*)(g1h + (size_t)r * 64 + c0) = pk.u;
}

// FUSED gather64 + gemm2. 32 nodes/block, 8 thr/node x 8 ch gather ->
// x2 = relu(dinv*acc + b1) -> LDS tile -> g2h = fp16(dinv .* (x2 @ W2)).
__global__ __launch_bounds__(TPB) void k_gfuse(const __half* __restrict__ g1h,
                                               const int* __restrict__ colpk,
                                               const int2* __restrict__ rowseg,
                                               const float* __restrict__ dinv,
                                               const float* __restrict__ W2,
                                               const float* __restrict__ b1,
                                               __half* __restrict__ g2h, int n) {
  __shared__ float W2l[64 * 32];
  __shared__ float b1l[64];
  __shared__ float x2l[32 * XSTR];
  int t = threadIdx.x;
  {
    const float4* W4 = (const float4*)W2;
    float4* Wl4 = (float4*)W2l;
#pragma unroll
    for (int i = 0; i < 2; ++i) Wl4[t + TPB * i] = W4[t + TPB * i];
    if (t < 64) b1l[t] = b1[t];
  }
  int node = t >> 3;
  int r = blockIdx.x * 32 + node;
  int c0 = (t & 7) << 3;
  bool valid = (r < n);
  float a[8];
  float dv = 0.f;
  if (valid) {
    dv = dinv[r];
    hpack8 s; s.u = *(const uint4*)(g1h + (size_t)r * 64 + c0);  // self-loop
#pragma unroll
    for (int k = 0; k < 4; ++k) {
      float2 f = __half22float2(s.h[k]);
      a[2 * k] = f.x; a[2 * k + 1] = f.y;
    }
    int2 seg = rowseg[r];
    int j = seg.x;
    for (; j + 7 < seg.y; j += 8) {
      int4 qa = *(const int4*)(colpk + j);
      int4 qb = *(const int4*)(colpk + j + 4);
      hpack8 u0; u0.u = *(const uint4*)(g1h + (size_t)(qa.x & 0x1FFFF) * 64 + c0);
      hpack8 u1; u1.u = *(const uint4*)(g1h + (size_t)(qa.y & 0x1FFFF) * 64 + c0);
      hpack8 u2; u2.u = *(const uint4*)(g1h + (size_t)(qa.z & 0x1FFFF) * 64 + c0);
      hpack8 u3; u3.u = *(const uint4*)(g1h + (size_t)(qa.w & 0x1FFFF) * 64 + c0);
      hpack8 u4; u4.u = *(const uint4*)(g1h + (size_t)(qb.x & 0x1FFFF) * 64 + c0);
      hpack8 u5; u5.u = *(const uint4*)(g1h + (size_t)(qb.y & 0x1FFFF) * 64 + c0);
      hpack8 u6; u6.u = *(const uint4*)(g1h + (size_t)(qb.z & 0x1FFFF) * 64 + c0);
      hpack8 u7; u7.u = *(const uint4*)(g1h + (size_t)(qb.w & 0x1FFFF) * 64 + c0);
      float w0 = dec_w(qa.x), w1 = dec_w(qa.y), w2 = dec_w(qa.z), w3 = dec_w(qa.w);
      float w4 = dec_w(qb.x), w5 = dec_w(qb.y), w6 = dec_w(qb.z), w7 = dec_w(qb.w);
#pragma unroll
      for (int k = 0; k < 4; ++k) {
        float2 f;
        f = __half22float2(u0.h[k]); a[2*k] += w0 * f.x; a[2*k+1] += w0 * f.y;
        f = __half22float2(u1.h[k]); a[2*k] += w1 * f.x; a[2*k+1] += w1 * f.y;
        f = __half22float2(u2.h[k]); a[2*k] += w2 * f.x; a[2*k+1] += w2 * f.y;
        f = __half22float2(u3.h[k]); a[2*k] += w3 * f.x; a[2*k+1] += w3 * f.y;
        f = __half22float2(u4.h[k]); a[2*k] += w4 * f.x; a[2*k+1] += w4 * f.y;
        f = __half22float2(u5.h[k]); a[2*k] += w5 * f.x; a[2*k+1] += w5 * f.y;
        f = __half22float2(u6.h[k]); a[2*k] += w6 * f.x; a[2*k+1] += w6 * f.y;
        f = __half22float2(u7.h[k]); a[2*k] += w7 * f.x; a[2*k+1] += w7 * f.y;
      }
    }
    if (j < seg.y) {  // exactly 4 remain (x4-padded)
      int4 qa = *(const int4*)(colpk + j);
      hpack8 u0; u0.u = *(const uint4*)(g1h + (size_t)(qa.x & 0x1FFFF) * 64 + c0);
      hpack8 u1; u1.u = *(const uint4*)(g1h + (size_t)(qa.y & 0x1FFFF) * 64 + c0);
      hpack8 u2; u2.u = *(const uint4*)(g1h + (size_t)(qa.z & 0x1FFFF) * 64 + c0);
      hpack8 u3; u3.u = *(const uint4*)(g1h + (size_t)(qa.w & 0x1FFFF) * 64 + c0);
      float w0 = dec_w(qa.x), w1 = dec_w(qa.y), w2 = dec_w(qa.z), w3 = dec_w(qa.w);
#pragma unroll
      for (int k = 0; k < 4; ++k) {
        float2 f;
        f = __half22float2(u0.h[k]); a[2*k] += w0 * f.x; a[2*k+1] += w0 * f.y;
        f = __half22float2(u1.h[k]); a[2*k] += w1 * f.x; a[2*k+1] += w1 * f.y;
        f = __half22float2(u2.h[k]); a[2*k] += w2 * f.x; a[2*k+1] += w2 * f.y;
        f = __half22float2(u3.h[k]); a[2*k] += w3 * f.x; a[2*k+1] += w3 * f.y;
      }
    }
    float* xp = x2l + node * XSTR + c0;
#pragma unroll
    for (int k = 0; k < 8; k += 4) {
      float4 v = {fmaxf(dv * a[k + 0] + b1l[c0 + k + 0], 0.f),
                  fmaxf(dv * a[k + 1] + b1l[c0 + k + 1], 0.f),
                  fmaxf(dv * a[k + 2] + b1l[c0 + k + 2], 0.f),
                  fmaxf(dv * a[k + 3] + b1l[c0 + k + 3], 0.f)};
      *(float4*)(xp + k) = v;
    }
  }
  __syncthreads();
  if (!valid) return;
  int oc = (t & 7) << 2;
  const float* xr = x2l + node * XSTR;
  float ax = 0.f, ay = 0.f, az = 0.f, aw = 0.f;
#pragma unroll
  for (int kk = 0; kk < 16; ++kk) {
    float4 xv = *(const float4*)(xr + 4 * kk);
    const float* w = &W2l[(kk * 4) * 32 + oc];
    float4 w0 = *(const float4*)(w);
    float4 w1 = *(const float4*)(w + 32);
    float4 w2 = *(const float4*)(w + 64);
    float4 w3 = *(const float4*)(w + 96);
    ax += xv.x * w0.x + xv.y * w1.x + xv.z * w2.x + xv.w * w3.x;
    ay += xv.x * w0.y + xv.y * w1.y + xv.z * w2.y + xv.w * w3.y;
    az += xv.x * w0.z + xv.y * w1.z + xv.z * w2.z + xv.w * w3.z;
    aw += xv.x * w0.w + xv.y * w1.w + xv.z * w2.w + xv.w * w3.w;
  }
  hpack pk;
  pk.h[0] = __floats2half2_rn(dv * ax, dv * ay);
  pk.h[1] = __floats2half2_rn(dv * az, dv * aw);
  *(uint2*)(g2h + (size_t)r * 32 + oc) = pk.u;
}

// out[r] = dinv[r]*(g2h[r] + sum_j w_j*g2h[src_j]) + b2. 4 thr/node x 8 ch.
__global__ __launch_bounds__(TPB) void k_gather32(const __half* __restrict__ g2h,
                                                  const int* __restrict__ colpk,
                                                  const int2* __restrict__ rowseg,
                                                  const float* __restrict__ dinv,
                                                  const float* __restrict__ b2,
                                                  float* __restrict__ out, int n) {
  int t = threadIdx.x;
  int r = blockIdx.x * 64 + (t >> 2);
  if (r >= n) return;
  int c0 = (t & 3) << 3;
  float a[8];
  {
    hpack8 s; s.u = *(const uint4*)(g2h + (size_t)r * 32 + c0);  // self-loop
#pragma unroll
    for (int k = 0; k < 4; ++k) {
      float2 f = __half22float2(s.h[k]);
      a[2 * k] = f.x; a[2 * k + 1] = f.y;
    }
  }
  int2 seg = rowseg[r];
  int j = seg.x;
  for (; j + 7 < seg.y; j += 8) {
    int4 qa = *(const int4*)(colpk + j);
    int4 qb = *(const int4*)(colpk + j + 4);
    hpack8 u0; u0.u = *(const uint4*)(g2h + (size_t)(qa.x & 0x1FFFF) * 32 + c0);
    hpack8 u1; u1.u = *(const uint4*)(g2h + (size_t)(qa.y & 0x1FFFF) * 32 + c0);
    hpack8 u2; u2.u = *(const uint4*)(g2h + (size_t)(qa.z & 0x1FFFF) * 32 + c0);
    hpack8 u3; u3.u = *(const uint4*)(g2h + (size_t)(qa.w & 0x1FFFF) * 32 + c0);
    hpack8 u4; u4.u = *(const uint4*)(g2h + (size_t)(qb.x & 0x1FFFF) * 32 + c0);
    hpack8 u5; u5.u = *(const uint4*)(g2h + (size_t)(qb.y & 0x1FFFF) * 32 + c0);
    hpack8 u6; u6.u = *(const uint4*)(g2h + (size_t)(qb.z & 0x1FFFF) * 32 + c0);
    hpack8 u7; u7.u = *(const uint4*)(g2h + (size_t)(qb.w & 0x1FFFF) * 32 + c0);
    float w0 = dec_w(qa.x), w1 = dec_w(qa.y), w2 = dec_w(qa.z), w3 = dec_w(qa.w);
    float w4 = dec_w(qb.x), w5 = dec_w(qb.y), w6 = dec_w(qb.z), w7 = dec_w(qb.w);
#pragma unroll
    for (int k = 0; k < 4; ++k) {
      float2 f;
      f = __half22float2(u0.h[k]); a[2*k] += w0 * f.x; a[2*k+1] += w0 * f.y;
      f = __half22float2(u1.h[k]); a[2*k] += w1 * f.x; a[2*k+1] += w1 * f.y;
      f = __half22float2(u2.h[k]); a[2*k] += w2 * f.x; a[2*k+1] += w2 * f.y;
      f = __half22float2(u3.h[k]); a[2*k] += w3 * f.x; a[2*k+1] += w3 * f.y;
      f = __half22float2(u4.h[k]); a[2*k] += w4 * f.x; a[2*k+1] += w4 * f.y;
      f = __half22float2(u5.h[k]); a[2*k] += w5 * f.x; a[2*k+1] += w5 * f.y;
      f = __half22float2(u6.h[k]); a[2*k] += w6 * f.x; a[2*k+1] += w6 * f.y;
      f = __half22float2(u7.h[k]); a[2*k] += w7 * f.x; a[2*k+1] += w7 * f.y;
    }
  }
  if (j < seg.y) {  // exactly 4 remain
    int4 qa = *(const int4*)(colpk + j);
    hpack8 u0; u0.u = *(const uint4*)(g2h + (size_t)(qa.x & 0x1FFFF) * 32 + c0);
    hpack8 u1; u1.u = *(const uint4*)(g2h + (size_t)(qa.y & 0x1FFFF) * 32 + c0);
    hpack8 u2; u2.u = *(const uint4*)(g2h + (size_t)(qa.z & 0x1FFFF) * 32 + c0);
    hpack8 u3; u3.u = *(const uint4*)(g2h + (size_t)(qa.w & 0x1FFFF) * 32 + c0);
    float w0 = dec_w(qa.x), w1 = dec_w(qa.y), w2 = dec_w(qa.z), w3 = dec_w(qa.w);
#pragma unroll
    for (int k = 0; k < 4; ++k) {
      float2 f;
      f = __half22float2(u0.h[k]); a[2*k] += w0 * f.x; a[2*k+1] += w0 * f.y;
      f = __half22float2(u1.h[k]); a[2*k] += w1 * f.x; a[2*k+1] += w1 * f.y;
      f = __half22float2(u2.h[k]); a[2*k] += w2 * f.x; a[2*k+1] += w2 * f.y;
      f = __half22float2(u3.h[k]); a[2*k] += w3 * f.x; a[2*k+1] += w3 * f.y;
    }
  }
  float dv = dinv[r];
  const float4* b24 = (const float4*)(b2 + c0);
  float4 bb0 = b24[0], bb1 = b24[1];
  float* op = out + (size_t)r * 32 + c0;
  *(float4*)(op)     = make_float4(dv * a[0] + bb0.x, dv * a[1] + bb0.y,
                                   dv * a[2] + bb0.z, dv * a[3] + bb0.w);
  *(float4*)(op + 4) = make_float4(dv * a[4] + bb1.x, dv * a[5] + bb1.y,
                                   dv * a[6] + bb1.z, dv * a[7] + bb1.w);
}

extern "C" void kernel_launch(void* const* d_in, const int* in_sizes, int n_in,
                              void* d_out, int out_size, void* d_ws, size_t ws_size,
                              hipStream_t stream) {
  const float* x  = (const float*)d_in[0];
  const int* ei   = (const int*)d_in[1];
  const float* ew = (const float*)d_in[2];
  const float* W1 = (const float*)d_in[3];
  const float* b1 = (const float*)d_in[4];
  const float* W2 = (const float*)d_in[5];
  const float* b2 = (const float*)d_in[6];
  float* out = (float*)d_out;

  const int n = in_sizes[0] / 64;  // 100000
  const int e = in_sizes[1] / 2;   // 1600000
  const int* si = ei;
  const int* di = ei + e;
  const int NBc = (n + BN2 - 1) >> BSH2;  // 391 coarse buckets

  // workspace layout (float-sized units), ~55 MB.
  float* ws = (float*)d_ws;
  const size_t NP = 100352;
  const size_t SLOTS = (size_t)NBC * CAP2;            // 2.88M
  float*  dinv   = ws;                                // [NP]
  __half* g1h    = (__half*)(ws + NP);                // [n*64 halves]
  int2*   rowseg = (int2*)(ws + NP + (size_t)n * 32); // [NP]
  int*    bpos   = (int*)(rowseg + NP);               // [NBC] counts (memset 0)
  int*    colpk  = bpos + 1024;                       // [SLOTS] 4B entries
  int2*   tin    = (int2*)(colpk + SLOTS);            // [SLOTS] int2
  __half* g2h    = (__half*)(tin + SLOTS);            // [n*32 halves]

  int gb_part = (e + PCHUNK - 1) / PCHUNK;  // 391
  int gb_g1 = (n + 15) / 16;
  int gb_gf = (n + 31) / 32;
  int gb_g32 = (n + 63) / 64;

  hipMemsetAsync(bpos, 0, NBC * sizeof(int), stream);
  k_part<<<gb_part, TPB_P, 0, stream>>>(si, di, ew, bpos, tin, e);
  k_sortb<<<NBc, TPB_S, 0, stream>>>(tin, bpos, colpk, rowseg, dinv, n);
  k_gemm1<<<gb_g1, TPB, 0, stream>>>(x, W1, dinv, g1h, n);
  k_gfuse<<<gb_gf, TPB, 0, stream>>>(g1h, colpk, rowseg, dinv, W2, b1, g2h, n);
  k_gather32<<<gb_g32, TPB, 0, stream>>>(g2h, colpk, rowseg, dinv, b2, out, n);
}

// Round 18
// 201.150 us; speedup vs baseline: 1.0321x; 1.0037x over previous
//
#include <hip/hip_runtime.h>
#include <hip/hip_fp16.h>

// 2-layer GCN (PyG GCNConv), fp32 math — per-node CSR gather, fp16 payloads,
// 4-byte colpk edge entries. Round-18: r16 config (TPB_S=1024, 391 buckets,
// 201.9 us) + RACE FIX in k_gfuse: b1l was staged by wave 0 and read in the
// pre-barrier gather epilogue by waves 1-3 with no __syncthreads between —
// latent since r12; r17's timing shift exposed it (post-timing absmax 8.6e-2).
// Fix: __syncthreads() right after W2l/b1l staging.
//
// g1h = fp16( dinv .* (x@W1) )
// acc[r] = g1h[r] + sum_{e:dst=r} w_e * g1h[src_e]   (fp32 regs; self w=1)
// x2 = relu(dinv[r]*acc[r] + b1);  g2h = fp16( dinv .* (x2@W2) )   [fused]
// out[r] = dinv[r]*(g2h[r] + sum_j w_j*g2h[src_j]) + b2

#define TPB 256
#define TPB_P 512
#define TPB_S 1024
#define BSH2 8
#define BN2 256          // nodes per coarse bucket
#define NBC 512          // coarse bucket slots (391 used)
#define PCHUNK 4096
#define CAP2 5632        // slots/bucket: 4096 avg + 11sigma + <=3/node pads
#define XSTR 68          // x2 LDS row stride (floats)

typedef union { uint2 u; __half2 h[2]; } hpack;
typedef union { uint4 u; __half2 h[4]; } hpack8;

__device__ __forceinline__ int enc_w(float w) {  // bf16 RNE, sign dropped
  unsigned b = __float_as_uint(w);
  return (int)(((b + 0x7FFFu + ((b >> 16) & 1u)) >> 16) & 0x7FFFu);
}
__device__ __forceinline__ float dec_w(int e) {
  return __uint_as_float(((unsigned)e >> 17) << 16);
}

// phase A: per-chunk LDS counting sort by coarse bucket, then linear copy-out.
// tin entry = (src | dl8<<17, ew fp32). bpos[b] = running count (memset 0).
__global__ __launch_bounds__(TPB_P) void k_part(const int* __restrict__ si,
                                                const int* __restrict__ di,
                                                const float* __restrict__ ew,
                                                int* __restrict__ bpos,
                                                int2* __restrict__ tin, int e) {
  __shared__ int hcnt[NBC];
  __shared__ int lst0[NBC];
  __shared__ int lcur[NBC];
  __shared__ int hbase[NBC];
  __shared__ int2 se[PCHUNK];
  __shared__ unsigned short sbk[PCHUNK];
  int t = threadIdx.x;
  int lo = blockIdx.x * PCHUNK;
  int hi = lo + PCHUNK; if (hi > e) hi = e;
  int cn = hi - lo;
  hcnt[t] = 0;  // TPB_P == NBC
  __syncthreads();
  for (int i = lo + t; i < hi; i += TPB_P) atomicAdd(&hcnt[di[i] >> BSH2], 1);
  __syncthreads();
  int c = hcnt[t];
  for (int off = 1; off < NBC; off <<= 1) {
    int u = (t >= off) ? hcnt[t - off] : 0;
    __syncthreads();
    hcnt[t] += u;
    __syncthreads();
  }
  {
    int ex = hcnt[t] - c;
    lst0[t] = ex;
    lcur[t] = 0;
    hbase[t] = c ? (t * CAP2 + atomicAdd(&bpos[t], c)) : 0;
  }
  __syncthreads();
  for (int i = lo + t; i < hi; i += TPB_P) {
    int d = di[i];
    int bk = d >> BSH2;
    int loc = atomicAdd(&lcur[bk], 1);
    int p = lst0[bk] + loc;
    se[p] = make_int2(si[i] | ((d & (BN2 - 1)) << 17), __float_as_int(ew[i]));
    sbk[p] = (unsigned short)bk;
  }
  __syncthreads();
  for (int p = t; p < cn; p += TPB_P) {  // sequential stores within runs
    int bk = sbk[p];
    tin[hbase[bk] + (p - lst0[bk])] = se[p];
  }
}

// phase B: per-coarse-bucket (256 nodes) counting sort -> per-node 4B edge
// lists (x4-padded, 16B-aligned starts) + rowseg + dinv. 391 blocks x 1024.
__global__ __launch_bounds__(TPB_S) void k_sortb(const int2* __restrict__ tin,
                                                 const int* __restrict__ bpos,
                                                 int* __restrict__ colpk,
                                                 int2* __restrict__ rowseg,
                                                 float* __restrict__ dinv, int n) {
  __shared__ int cnt[BN2];
  __shared__ float degw[BN2];
  __shared__ int cur[BN2];
  __shared__ int ls[BN2];
  int b = blockIdx.x, t = threadIdx.x;
  if (t < BN2) { cnt[t] = 0; degw[t] = 1.0f; }  // self-loop weight
  __syncthreads();
  int jb = b * CAP2, je = jb + bpos[b];
  for (int j = jb + t; j < je; j += TPB_S) {
    int2 p = tin[j];
    int dl = p.x >> 17;
    atomicAdd(&cnt[dl], 1);
    atomicAdd(&degw[dl], __int_as_float(p.y));  // fp32 degree
  }
  __syncthreads();
  int c = (t < BN2) ? cnt[t] : 0;
  int c4 = (c + 3) & ~3;  // pad to multiple of 4 entries (16B)
  if (t < BN2) ls[t] = c4;
  __syncthreads();
  for (int off = 1; off < BN2; off <<= 1) {
    int u = (t >= off && t < BN2) ? ls[t - off] : 0;
    __syncthreads();
    if (t < BN2) ls[t] += u;
    __syncthreads();
  }
  int base = b << BSH2;
  if (t < BN2) {
    int start = jb + ls[t] - c4;  // 4-aligned offset -> 16B-aligned
    cur[t] = start;
    int node = base + t;
    if (node < n) {
      rowseg[node] = make_int2(start, start + c4);
      dinv[node] = rsqrtf(degw[t]);
    }
    for (int i = c; i < c4; ++i) colpk[start + i] = 0;  // zero-weight pads
  }
  __syncthreads();
  for (int j = jb + t; j < je; j += TPB_S) {
    int2 p = tin[j];
    int dl = p.x >> 17;
    int pos = atomicAdd(&cur[dl], 1);
    colpk[pos] = (p.x & 0x1FFFF) | (enc_w(__int_as_float(p.y)) << 17);
  }
}

// g1h = fp16(dinv .* (x @ W1)). 16 rows/block, 16 thr/row x 4 ch.
__global__ __launch_bounds__(TPB) void k_gemm1(const float* __restrict__ x,
                                               const float* __restrict__ W1,
                                               const float* __restrict__ dinv,
                                               __half* __restrict__ g1h, int n) {
  __shared__ float Wl[64 * 64];
  int t = threadIdx.x;
  {
    const float4* W4 = (const float4*)W1;
    float4* Wl4 = (float4*)Wl;
#pragma unroll
    for (int i = 0; i < 4; ++i) Wl4[t + TPB * i] = W4[t + TPB * i];
  }
  __syncthreads();
  int r = blockIdx.x * 16 + (t >> 4);
  if (r >= n) return;
  int c0 = (t & 15) << 2;
  const float4* xr = (const float4*)(x + (size_t)r * 64);
  float ax = 0.f, ay = 0.f, az = 0.f, aw = 0.f;
#pragma unroll
  for (int kk = 0; kk < 16; ++kk) {
    float4 xv = xr[kk];
    const float* w = &Wl[(kk * 4) * 64 + c0];
    float4 w0 = *(const float4*)(w);
    float4 w1 = *(const float4*)(w + 64);
    float4 w2 = *(const float4*)(w + 128);
    float4 w3 = *(const float4*)(w + 192);
    ax += xv.x * w0.x + xv.y * w1.x + xv.z * w2.x + xv.w * w3.x;
    ay += xv.x * w0.y + xv.y * w1.y + xv.z * w2.y + xv.w * w3.y;
    az += xv.x * w0.z + xv.y * w1.z + xv.z * w2.z + xv.w * w3.z;
    aw += xv.x * w0.w + xv.y * w1.w + xv.z * w2.w + xv.w * w3.w;
  }
  float dv = dinv[r];
  hpack pk;
  pk.h[0] = __floats2half2_rn(dv * ax, dv * ay);
  pk.h[1] = __floats2half2_rn(dv * az, dv * aw);
  *(uint2*)(g1h + (size_t)r * 64 + c0) = pk.u;
}

// FUSED gather64 + gemm2. 32 nodes/block, 8 thr/node x 8 ch gather ->
// x2 = relu(dinv*acc + b1) -> LDS tile -> g2h = fp16(dinv .* (x2 @ W2)).
__global__ __launch_bounds__(TPB) void k_gfuse(const __half* __restrict__ g1h,
                                               const int* __restrict__ colpk,
                                               const int2* __restrict__ rowseg,
                                               const float* __restrict__ dinv,
                                               const float* __restrict__ W2,
                                               const float* __restrict__ b1,
                                               __half* __restrict__ g2h, int n) {
  __shared__ float W2l[64 * 32];
  __shared__ float b1l[64];
  __shared__ float x2l[32 * XSTR];
  int t = threadIdx.x;
  {
    const float4* W4 = (const float4*)W2;
    float4* Wl4 = (float4*)W2l;
#pragma unroll
    for (int i = 0; i < 2; ++i) Wl4[t + TPB * i] = W4[t + TPB * i];
    if (t < 64) b1l[t] = b1[t];
  }
  __syncthreads();  // RACE FIX: b1l is read pre-GEMM-barrier in the epilogue
  int node = t >> 3;
  int r = blockIdx.x * 32 + node;
  int c0 = (t & 7) << 3;
  bool valid = (r < n);
  float a[8];
  float dv = 0.f;
  if (valid) {
    dv = dinv[r];
    hpack8 s; s.u = *(const uint4*)(g1h + (size_t)r * 64 + c0);  // self-loop
#pragma unroll
    for (int k = 0; k < 4; ++k) {
      float2 f = __half22float2(s.h[k]);
      a[2 * k] = f.x; a[2 * k + 1] = f.y;
    }
    int2 seg = rowseg[r];
    int j = seg.x;
    for (; j + 7 < seg.y; j += 8) {
      int4 qa = *(const int4*)(colpk + j);
      int4 qb = *(const int4*)(colpk + j + 4);
      hpack8 u0; u0.u = *(const uint4*)(g1h + (size_t)(qa.x & 0x1FFFF) * 64 + c0);
      hpack8 u1; u1.u = *(const uint4*)(g1h + (size_t)(qa.y & 0x1FFFF) * 64 + c0);
      hpack8 u2; u2.u = *(const uint4*)(g1h + (size_t)(qa.z & 0x1FFFF) * 64 + c0);
      hpack8 u3; u3.u = *(const uint4*)(g1h + (size_t)(qa.w & 0x1FFFF) * 64 + c0);
      hpack8 u4; u4.u = *(const uint4*)(g1h + (size_t)(qb.x & 0x1FFFF) * 64 + c0);
      hpack8 u5; u5.u = *(const uint4*)(g1h + (size_t)(qb.y & 0x1FFFF) * 64 + c0);
      hpack8 u6; u6.u = *(const uint4*)(g1h + (size_t)(qb.z & 0x1FFFF) * 64 + c0);
      hpack8 u7; u7.u = *(const uint4*)(g1h + (size_t)(qb.w & 0x1FFFF) * 64 + c0);
      float w0 = dec_w(qa.x), w1 = dec_w(qa.y), w2 = dec_w(qa.z), w3 = dec_w(qa.w);
      float w4 = dec_w(qb.x), w5 = dec_w(qb.y), w6 = dec_w(qb.z), w7 = dec_w(qb.w);
#pragma unroll
      for (int k = 0; k < 4; ++k) {
        float2 f;
        f = __half22float2(u0.h[k]); a[2*k] += w0 * f.x; a[2*k+1] += w0 * f.y;
        f = __half22float2(u1.h[k]); a[2*k] += w1 * f.x; a[2*k+1] += w1 * f.y;
        f = __half22float2(u2.h[k]); a[2*k] += w2 * f.x; a[2*k+1] += w2 * f.y;
        f = __half22float2(u3.h[k]); a[2*k] += w3 * f.x; a[2*k+1] += w3 * f.y;
        f = __half22float2(u4.h[k]); a[2*k] += w4 * f.x; a[2*k+1] += w4 * f.y;
        f = __half22float2(u5.h[k]); a[2*k] += w5 * f.x; a[2*k+1] += w5 * f.y;
        f = __half22float2(u6.h[k]); a[2*k] += w6 * f.x; a[2*k+1] += w6 * f.y;
        f = __half22float2(u7.h[k]); a[2*k] += w7 * f.x; a[2*k+1] += w7 * f.y;
      }
    }
    if (j < seg.y) {  // exactly 4 remain (x4-padded)
      int4 qa = *(const int4*)(colpk + j);
      hpack8 u0; u0.u = *(const uint4*)(g1h + (size_t)(qa.x & 0x1FFFF) * 64 + c0);
      hpack8 u1; u1.u = *(const uint4*)(g1h + (size_t)(qa.y & 0x1FFFF) * 64 + c0);
      hpack8 u2; u2.u = *(const uint4*)(g1h + (size_t)(qa.z & 0x1FFFF) * 64 + c0);
      hpack8 u3; u3.u = *(const uint4*)(g1h + (size_t)(qa.w & 0x1FFFF) * 64 + c0);
      float w0 = dec_w(qa.x), w1 = dec_w(qa.y), w2 = dec_w(qa.z), w3 = dec_w(qa.w);
#pragma unroll
      for (int k = 0; k < 4; ++k) {
        float2 f;
        f = __half22float2(u0.h[k]); a[2*k] += w0 * f.x; a[2*k+1] += w0 * f.y;
        f = __half22float2(u1.h[k]); a[2*k] += w1 * f.x; a[2*k+1] += w1 * f.y;
        f = __half22float2(u2.h[k]); a[2*k] += w2 * f.x; a[2*k+1] += w2 * f.y;
        f = __half22float2(u3.h[k]); a[2*k] += w3 * f.x; a[2*k+1] += w3 * f.y;
      }
    }
    float* xp = x2l + node * XSTR + c0;
#pragma unroll
    for (int k = 0; k < 8; k += 4) {
      float4 v = {fmaxf(dv * a[k + 0] + b1l[c0 + k + 0], 0.f),
                  fmaxf(dv * a[k + 1] + b1l[c0 + k + 1], 0.f),
                  fmaxf(dv * a[k + 2] + b1l[c0 + k + 2], 0.f),
                  fmaxf(dv * a[k + 3] + b1l[c0 + k + 3], 0.f)};
      *(float4*)(xp + k) = v;
    }
  }
  __syncthreads();
  if (!valid) return;
  int oc = (t & 7) << 2;
  const float* xr = x2l + node * XSTR;
  float ax = 0.f, ay = 0.f, az = 0.f, aw = 0.f;
#pragma unroll
  for (int kk = 0; kk < 16; ++kk) {
    float4 xv = *(const float4*)(xr + 4 * kk);
    const float* w = &W2l[(kk * 4) * 32 + oc];
    float4 w0 = *(const float4*)(w);
    float4 w1 = *(const float4*)(w + 32);
    float4 w2 = *(const float4*)(w + 64);
    float4 w3 = *(const float4*)(w + 96);
    ax += xv.x * w0.x + xv.y * w1.x + xv.z * w2.x + xv.w * w3.x;
    ay += xv.x * w0.y + xv.y * w1.y + xv.z * w2.y + xv.w * w3.y;
    az += xv.x * w0.z + xv.y * w1.z + xv.z * w2.z + xv.w * w3.z;
    aw += xv.x * w0.w + xv.y * w1.w + xv.z * w2.w + xv.w * w3.w;
  }
  hpack pk;
  pk.h[0] = __floats2half2_rn(dv * ax, dv * ay);
  pk.h[1] = __floats2half2_rn(dv * az, dv * aw);
  *(uint2*)(g2h + (size_t)r * 32 + oc) = pk.u;
}

// out[r] = dinv[r]*(g2h[r] + sum_j w_j*g2h[src_j]) + b2. 4 thr/node x 8 ch.
__global__ __launch_bounds__(TPB) void k_gather32(const __half* __restrict__ g2h,
                                                  const int* __restrict__ colpk,
                                                  const int2* __restrict__ rowseg,
                                                  const float* __restrict__ dinv,
                                                  const float* __restrict__ b2,
                                                  float* __restrict__ out, int n) {
  int t = threadIdx.x;
  int r = blockIdx.x * 64 + (t >> 2);
  if (r >= n) return;
  int c0 = (t & 3) << 3;
  float a[8];
  {
    hpack8 s; s.u = *(const uint4*)(g2h + (size_t)r * 32 + c0);  // self-loop
#pragma unroll
    for (int k = 0; k < 4; ++k) {
      float2 f = __half22float2(s.h[k]);
      a[2 * k] = f.x; a[2 * k + 1] = f.y;
    }
  }
  int2 seg = rowseg[r];
  int j = seg.x;
  for (; j + 7 < seg.y; j += 8) {
    int4 qa = *(const int4*)(colpk + j);
    int4 qb = *(const int4*)(colpk + j + 4);
    hpack8 u0; u0.u = *(const uint4*)(g2h + (size_t)(qa.x & 0x1FFFF) * 32 + c0);
    hpack8 u1; u1.u = *(const uint4*)(g2h + (size_t)(qa.y & 0x1FFFF) * 32 + c0);
    hpack8 u2; u2.u = *(const uint4*)(g2h + (size_t)(qa.z & 0x1FFFF) * 32 + c0);
    hpack8 u3; u3.u = *(const uint4*)(g2h + (size_t)(qa.w & 0x1FFFF) * 32 + c0);
    hpack8 u4; u4.u = *(const uint4*)(g2h + (size_t)(qb.x & 0x1FFFF) * 32 + c0);
    hpack8 u5; u5.u = *(const uint4*)(g2h + (size_t)(qb.y & 0x1FFFF) * 32 + c0);
    hpack8 u6; u6.u = *(const uint4*)(g2h + (size_t)(qb.z & 0x1FFFF) * 32 + c0);
    hpack8 u7; u7.u = *(const uint4*)(g2h + (size_t)(qb.w & 0x1FFFF) * 32 + c0);
    float w0 = dec_w(qa.x), w1 = dec_w(qa.y), w2 = dec_w(qa.z), w3 = dec_w(qa.w);
    float w4 = dec_w(qb.x), w5 = dec_w(qb.y), w6 = dec_w(qb.z), w7 = dec_w(qb.w);
#pragma unroll
    for (int k = 0; k < 4; ++k) {
      float2 f;
      f = __half22float2(u0.h[k]); a[2*k] += w0 * f.x; a[2*k+1] += w0 * f.y;
      f = __half22float2(u1.h[k]); a[2*k] += w1 * f.x; a[2*k+1] += w1 * f.y;
      f = __half22float2(u2.h[k]); a[2*k] += w2 * f.x; a[2*k+1] += w2 * f.y;
      f = __half22float2(u3.h[k]); a[2*k] += w3 * f.x; a[2*k+1] += w3 * f.y;
      f = __half22float2(u4.h[k]); a[2*k] += w4 * f.x; a[2*k+1] += w4 * f.y;
      f = __half22float2(u5.h[k]); a[2*k] += w5 * f.x; a[2*k+1] += w5 * f.y;
      f = __half22float2(u6.h[k]); a[2*k] += w6 * f.x; a[2*k+1] += w6 * f.y;
      f = __half22float2(u7.h[k]); a[2*k] += w7 * f.x; a[2*k+1] += w7 * f.y;
    }
  }
  if (j < seg.y) {  // exactly 4 remain
    int4 qa = *(const int4*)(colpk + j);
    hpack8 u0; u0.u = *(const uint4*)(g2h + (size_t)(qa.x & 0x1FFFF) * 32 + c0);
    hpack8 u1; u1.u = *(const uint4*)(g2h + (size_t)(qa.y & 0x1FFFF) * 32 + c0);
    hpack8 u2; u2.u = *(const uint4*)(g2h + (size_t)(qa.z & 0x1FFFF) * 32 + c0);
    hpack8 u3; u3.u = *(const uint4*)(g2h + (size_t)(qa.w & 0x1FFFF) * 32 + c0);
    float w0 = dec_w(qa.x), w1 = dec_w(qa.y), w2 = dec_w(qa.z), w3 = dec_w(qa.w);
#pragma unroll
    for (int k = 0; k < 4; ++k) {
      float2 f;
      f = __half22float2(u0.h[k]); a[2*k] += w0 * f.x; a[2*k+1] += w0 * f.y;
      f = __half22float2(u1.h[k]); a[2*k] += w1 * f.x; a[2*k+1] += w1 * f.y;
      f = __half22float2(u2.h[k]); a[2*k] += w2 * f.x; a[2*k+1] += w2 * f.y;
      f = __half22float2(u3.h[k]); a[2*k] += w3 * f.x; a[2*k+1] += w3 * f.y;
    }
  }
  float dv = dinv[r];
  const float4* b24 = (const float4*)(b2 + c0);
  float4 bb0 = b24[0], bb1 = b24[1];
  float* op = out + (size_t)r * 32 + c0;
  *(float4*)(op)     = make_float4(dv * a[0] + bb0.x, dv * a[1] + bb0.y,
                                   dv * a[2] + bb0.z, dv * a[3] + bb0.w);
  *(float4*)(op + 4) = make_float4(dv * a[4] + bb1.x, dv * a[5] + bb1.y,
                                   dv * a[6] + bb1.z, dv * a[7] + bb1.w);
}

extern "C" void kernel_launch(void* const* d_in, const int* in_sizes, int n_in,
                              void* d_out, int out_size, void* d_ws, size_t ws_size,
                              hipStream_t stream) {
  const float* x  = (const float*)d_in[0];
  const int* ei   = (const int*)d_in[1];
  const float* ew = (const float*)d_in[2];
  const float* W1 = (const float*)d_in[3];
  const float* b1 = (const float*)d_in[4];
  const float* W2 = (const float*)d_in[5];
  const float* b2 = (const float*)d_in[6];
  float* out = (float*)d_out;

  const int n = in_sizes[0] / 64;  // 100000
  const int e = in_sizes[1] / 2;   // 1600000
  const int* si = ei;
  const int* di = ei + e;
  const int NBc = (n + BN2 - 1) >> BSH2;  // 391 coarse buckets

  // workspace layout (float-sized units), ~55 MB.
  float* ws = (float*)d_ws;
  const size_t NP = 100352;
  const size_t SLOTS = (size_t)NBc * CAP2;            // 2.20M
  float*  dinv   = ws;                                // [NP]
  __half* g1h    = (__half*)(ws + NP);                // [n*64 halves]
  int2*   rowseg = (int2*)(ws + NP + (size_t)n * 32); // [NP]
  int*    bpos   = (int*)(rowseg + NP);               // [NBC] counts (memset 0)
  int*    colpk  = bpos + 1024;                       // [SLOTS] 4B entries
  int2*   tin    = (int2*)(colpk + SLOTS);            // [SLOTS] int2
  __half* g2h    = (__half*)(tin + SLOTS);            // [n*32 halves]

  int gb_part = (e + PCHUNK - 1) / PCHUNK;  // 391
  int gb_g1 = (n + 15) / 16;
  int gb_gf = (n + 31) / 32;
  int gb_g32 = (n + 63) / 64;

  hipMemsetAsync(bpos, 0, NBC * sizeof(int), stream);
  k_part<<<gb_part, TPB_P, 0, stream>>>(si, di, ew, bpos, tin, e);
  k_sortb<<<NBc, TPB_S, 0, stream>>>(tin, bpos, colpk, rowseg, dinv, n);
  k_gemm1<<<gb_g1, TPB, 0, stream>>>(x, W1, dinv, g1h, n);
  k_gfuse<<<gb_gf, TPB, 0, stream>>>(g1h, colpk, rowseg, dinv, W2, b1, g2h, n);
  k_gather32<<<gb_g32, TPB, 0, stream>>>(g2h, colpk, rowseg, dinv, b2, out, n);
}